// Round 4
// baseline (558.077 us; speedup 1.0000x reference)
//
#include <hip/hip_runtime.h>

typedef unsigned short ushort_t;
typedef unsigned int uint_t;
typedef _Float16 f16;
typedef f16 f16x8 __attribute__((ext_vector_type(8)));
typedef float f32x4 __attribute__((ext_vector_type(4)));

#define B_   16
#define S_   128
#define T_   1024
#define M_   16
#define H_   1024
#define OUTW 3094
#define NSPAN (B_*S_)      /* 2048  */
#define NROW  (NSPAN*M_)   /* 32768 */

// ---------- ws layout (bytes) ----------
#define WS_CONT   0                       /* f16  [32768][1024]   67,108,864 B */
#define WS_DOCT   67108864                /* f16  [16][1024][1024] 33,554,432 B */
#define WS_W1T    100663296               /* f16  [1024][1024]     2,097,152 B */
#define WS_SCORES 102760448               /* f32  [32768]            131,072 B */

// clamp that also kills NaN (fmaxf/fminf return the non-NaN operand)
__device__ __forceinline__ float sane(float v) {
  return fminf(fmaxf(v, -60000.f), 60000.f);
}
__device__ __forceinline__ ushort_t f16bits(float f) {
  union { f16 h; ushort_t u; } c; c.h = (f16)f; return c.u;
}
__device__ __forceinline__ void load_lds16(const void* g, void* l) {
  __builtin_amdgcn_global_load_lds(
      (const __attribute__((address_space(1))) uint_t*)g,
      (__attribute__((address_space(3))) uint_t*)l, 16, 0, 0);
}

// ---------------------------------------------------------------------------
// Transpose + f32->f16 convert: in f32 [z][R][C] -> out f16 [z][C][R]
// ---------------------------------------------------------------------------
__global__ __launch_bounds__(256) void tconv(const float* __restrict__ in,
                                             ushort_t* __restrict__ out,
                                             int R, int C) {
  __shared__ uint_t tile[64][65];
  const int tid = threadIdx.x;
  const int c0 = blockIdx.x * 64, r0 = blockIdx.y * 64;
  const size_t mo = (size_t)blockIdx.z * R * C;
  const float* ip = in + mo;
  ushort_t* op = out + mo;
  const int tx = tid & 63, ty = tid >> 6;
#pragma unroll
  for (int p = 0; p < 16; ++p) {
    int r = p * 4 + ty;
    tile[r][tx] = (uint_t)f16bits(ip[(size_t)(r0 + r) * C + c0 + tx]);
  }
  __syncthreads();
  const int rr = (tid & 31) * 2, cc0 = tid >> 5;  // cc0 in 0..7
  uint_t* op32 = (uint_t*)op;
#pragma unroll
  for (int p = 0; p < 8; ++p) {
    int c = cc0 + p * 8;
    uint_t lo = tile[rr][c] & 0xffffu;
    uint_t hi = tile[rr + 1][c] & 0xffffu;
    op32[((size_t)(c0 + c) * R + r0 + rr) >> 1] = lo | (hi << 16);
  }
}

// ---------------------------------------------------------------------------
// GEMM1 (ROUND 4): issue-early / write-late distance-2 pipeline.
//   iter kt: issue A(kt+2) regs + B(kt+2) gload_lds -> Bs[rot],
//            ds_read frags of tile kt, 16 MFMA,
//            s_waitcnt vmcnt(6)  (leaves exactly the kt+2 group in flight;
//            A(kt+1) regs + B(kt+1) glds proven landed),
//            cvt A(kt+1) regs -> ds_write As[rot],
//            lgkmcnt(0) + raw s_barrier + sched_barrier(0).
// A regs get a FULL iteration of latency coverage (round-2 flaw: same-iter
// issue+consume = ~0 coverage). LDS 2x8K A + 3x8K B = 40KB -> 4 blocks/CU.
// ---------------------------------------------------------------------------
__device__ __forceinline__ void g1_step(
    int kk, const float* __restrict__ aSrc, const ushort_t* __restrict__ Bp,
    f16*& aRd, f16*& aWr, f16*& bRd, f16*& bMid, f16*& bWr,
    f32x4& P0, f32x4& P1, f32x4& P2, f32x4& P3,
    f32x4& Q0, f32x4& Q1, f32x4& Q2, f32x4& Q3,
    f32x4 (&acc)[4][4],
    int w, int brow, int bcol, int arow, int ac0, int ac1,
    int wr, int wc, int quad, int l16) {
  // 1. issue A(kt+2) into Q
  const float* ap = aSrc + kk + 64;
  Q0 = *(const f32x4*)(ap + 0);
  Q1 = *(const f32x4*)(ap + 4);
  Q2 = *(const f32x4*)(ap + 8);
  Q3 = *(const f32x4*)(ap + 12);
  // 2. issue B(kt+2) glds into bWr
#pragma unroll
  for (int i = 0; i < 2; ++i) {
    const int rb = w * 32 + i * 16;
    load_lds16(Bp + (size_t)(rb + brow) * T_ + kk + 64 + bcol, bWr + rb * 32);
  }
  // 3. fragment reads of tile kt
  f16x8 af[4], bfr[4];
#pragma unroll
  for (int i = 0; i < 4; ++i) {
    const int row = wr * 64 + i * 16 + l16;
    const int sw = (row >> 1) & 3;
    af[i] = *(const f16x8*)(aRd + row * 32 + ((quad ^ sw) * 8));
  }
#pragma unroll
  for (int j = 0; j < 4; ++j) {
    const int row = wc * 64 + j * 16 + l16;
    const int sw = (row >> 1) & 3;
    bfr[j] = *(const f16x8*)(bRd + row * 32 + ((quad ^ sw) * 8));
  }
#pragma unroll
  for (int i = 0; i < 4; ++i)
#pragma unroll
    for (int j = 0; j < 4; ++j)
      acc[i][j] = __builtin_amdgcn_mfma_f32_16x16x32_f16(af[i], bfr[j], acc[i][j], 0, 0, 0);
  // 4. counted wait: everything issued before this step is drained
  asm volatile("s_waitcnt vmcnt(6)" ::: "memory");
  // 5. write-late: cvt A(kt+1) regs (issued one full iteration ago)
  f16x8 h0, h1;
#pragma unroll
  for (int k = 0; k < 4; ++k) {
    h0[k] = (f16)P0[k]; h0[k + 4] = (f16)P1[k];
    h1[k] = (f16)P2[k]; h1[k + 4] = (f16)P3[k];
  }
  *(f16x8*)(aWr + arow * 32 + ac0) = h0;
  *(f16x8*)(aWr + arow * 32 + ac1) = h1;
  asm volatile("s_waitcnt lgkmcnt(0)" ::: "memory");
  __builtin_amdgcn_s_barrier();
  __builtin_amdgcn_sched_barrier(0);
  // 6. rotate buffers
  { f16* t = aRd; aRd = aWr; aWr = t; }
  { f16* t = bRd; bRd = bMid; bMid = bWr; bWr = t; }
}

__global__ __launch_bounds__(256, 4) void gemm1(const float* __restrict__ startm,
                                                const float* __restrict__ endm,
                                                const float* __restrict__ contm,
                                                const ushort_t* __restrict__ docT,
                                                float* __restrict__ out,
                                                f16* __restrict__ contF) {
  __shared__ f16 As0[128 * 32], As1[128 * 32];              // 2 x 8KB
  __shared__ f16 Bs0[128 * 32], Bs1[128 * 32], Bs2[128 * 32]; // 3 x 8KB
  const int tid = threadIdx.x;
  const uint_t pid = blockIdx.x;
  const int xcd = pid & 7;
  const int s_  = pid >> 3;
  const int ct  = s_ & 7;
  const int pg  = (s_ >> 3) * 8 + xcd;   // 0..287
  const int rt  = pg >> 4;
  const int b   = pg & 15;

  const float* Ap;
  if (rt == 0)      Ap = startm + (size_t)b * S_ * T_;
  else if (rt == 1) Ap = endm + (size_t)b * S_ * T_;
  else              Ap = contm + (size_t)b * (S_ * M_ * T_) + (size_t)(rt - 2) * 128 * T_;
  const ushort_t* Bp = docT + (size_t)b * (H_ * T_) + (size_t)ct * 128 * T_;

  const int lane = tid & 63, w = tid >> 6;
  const int wr = w >> 1, wc = w & 1;
  const int quad = lane >> 4, l16 = lane & 15;
  const int arow = tid >> 1;                 // 0..127
  const int ah   = tid & 1;                  // 0/1 -> k offset ah*16
  const int asw  = (arow >> 1) & 3;
  const int ac0  = ((2 * ah) ^ asw) * 8;
  const int ac1  = ((2 * ah + 1) ^ asw) * 8;
  const float* aSrc = Ap + (size_t)arow * T_ + ah * 16;
  const int brow = lane >> 2;
  const int bcol = ((lane & 3) ^ ((lane >> 3) & 3)) * 8;

  f32x4 acc[4][4];
#pragma unroll
  for (int i = 0; i < 4; ++i)
#pragma unroll
    for (int j = 0; j < 4; ++j) acc[i][j] = (f32x4){0.f, 0.f, 0.f, 0.f};

  f16* aRd = As0; f16* aWr = As1;
  f16* bRd = Bs0; f16* bMid = Bs1; f16* bWr = Bs2;
  f32x4 P0, P1, P2, P3, Q0, Q1, Q2, Q3;

  // ---- prologue: A0 regs, B0 glds, A1 regs(P), B1 glds; vmcnt(6); A0->LDS ----
  {
    f32x4 r0 = *(const f32x4*)(aSrc + 0);
    f32x4 r1 = *(const f32x4*)(aSrc + 4);
    f32x4 r2 = *(const f32x4*)(aSrc + 8);
    f32x4 r3 = *(const f32x4*)(aSrc + 12);
#pragma unroll
    for (int i = 0; i < 2; ++i) {
      const int rb = w * 32 + i * 16;
      load_lds16(Bp + (size_t)(rb + brow) * T_ + bcol, bRd + rb * 32);
    }
    P0 = *(const f32x4*)(aSrc + 32);
    P1 = *(const f32x4*)(aSrc + 36);
    P2 = *(const f32x4*)(aSrc + 40);
    P3 = *(const f32x4*)(aSrc + 44);
#pragma unroll
    for (int i = 0; i < 2; ++i) {
      const int rb = w * 32 + i * 16;
      load_lds16(Bp + (size_t)(rb + brow) * T_ + 32 + bcol, bMid + rb * 32);
    }
    asm volatile("s_waitcnt vmcnt(6)" ::: "memory");
    f16x8 h0, h1;
#pragma unroll
    for (int k = 0; k < 4; ++k) {
      h0[k] = (f16)r0[k]; h0[k + 4] = (f16)r1[k];
      h1[k] = (f16)r2[k]; h1[k + 4] = (f16)r3[k];
    }
    *(f16x8*)(aRd + arow * 32 + ac0) = h0;
    *(f16x8*)(aRd + arow * 32 + ac1) = h1;
    asm volatile("s_waitcnt lgkmcnt(0)" ::: "memory");
    __builtin_amdgcn_s_barrier();
    __builtin_amdgcn_sched_barrier(0);
  }

  // ---- steady state: kt = 0..29, unrolled by 2 for P/Q rotation ----
  int kk = 0;
#pragma unroll 1
  for (int it = 0; it < 15; ++it) {
    g1_step(kk, aSrc, Bp, aRd, aWr, bRd, bMid, bWr,
            P0, P1, P2, P3, Q0, Q1, Q2, Q3, acc,
            w, brow, bcol, arow, ac0, ac1, wr, wc, quad, l16);
    kk += 32;
    g1_step(kk, aSrc, Bp, aRd, aWr, bRd, bMid, bWr,
            Q0, Q1, Q2, Q3, P0, P1, P2, P3, acc,
            w, brow, bcol, arow, ac0, ac1, wr, wc, quad, l16);
    kk += 32;
  }
  // After loop: aRd = A30 buf, aWr free; bRd = B30, bMid = B31; P = A31 regs.

  // ---- peel kt=30: compute tile 30, write A31 to LDS ----
  {
    f16x8 af[4], bfr[4];
#pragma unroll
    for (int i = 0; i < 4; ++i) {
      const int row = wr * 64 + i * 16 + l16;
      const int sw = (row >> 1) & 3;
      af[i] = *(const f16x8*)(aRd + row * 32 + ((quad ^ sw) * 8));
    }
#pragma unroll
    for (int j = 0; j < 4; ++j) {
      const int row = wc * 64 + j * 16 + l16;
      const int sw = (row >> 1) & 3;
      bfr[j] = *(const f16x8*)(bRd + row * 32 + ((quad ^ sw) * 8));
    }
#pragma unroll
    for (int i = 0; i < 4; ++i)
#pragma unroll
      for (int j = 0; j < 4; ++j)
        acc[i][j] = __builtin_amdgcn_mfma_f32_16x16x32_f16(af[i], bfr[j], acc[i][j], 0, 0, 0);
    asm volatile("s_waitcnt vmcnt(0)" ::: "memory");
    f16x8 h0, h1;
#pragma unroll
    for (int k = 0; k < 4; ++k) {
      h0[k] = (f16)P0[k]; h0[k + 4] = (f16)P1[k];
      h1[k] = (f16)P2[k]; h1[k + 4] = (f16)P3[k];
    }
    *(f16x8*)(aWr + arow * 32 + ac0) = h0;
    *(f16x8*)(aWr + arow * 32 + ac1) = h1;
    asm volatile("s_waitcnt lgkmcnt(0)" ::: "memory");
    __builtin_amdgcn_s_barrier();
    __builtin_amdgcn_sched_barrier(0);
  }
  // ---- peel kt=31: compute tile 31 (A in aWr, B in bMid) ----
  {
    f16x8 af[4], bfr[4];
#pragma unroll
    for (int i = 0; i < 4; ++i) {
      const int row = wr * 64 + i * 16 + l16;
      const int sw = (row >> 1) & 3;
      af[i] = *(const f16x8*)(aWr + row * 32 + ((quad ^ sw) * 8));
    }
#pragma unroll
    for (int j = 0; j < 4; ++j) {
      const int row = wc * 64 + j * 16 + l16;
      const int sw = (row >> 1) & 3;
      bfr[j] = *(const f16x8*)(bMid + row * 32 + ((quad ^ sw) * 8));
    }
#pragma unroll
    for (int i = 0; i < 4; ++i)
#pragma unroll
      for (int j = 0; j < 4; ++j)
        acc[i][j] = __builtin_amdgcn_mfma_f32_16x16x32_f16(af[i], bfr[j], acc[i][j], 0, 0, 0);
  }

  if (rt < 2) {
    float* op = out + (size_t)b * S_ * OUTW + (size_t)rt * 1024 + (size_t)ct * 128;
#pragma unroll
    for (int i = 0; i < 4; ++i)
#pragma unroll
      for (int j = 0; j < 4; ++j)
#pragma unroll
        for (int r = 0; r < 4; ++r) {
          int row = wr * 64 + i * 16 + quad * 4 + r;
          int col = wc * 64 + j * 16 + l16;
          op[(size_t)row * OUTW + col] = sane(acc[i][j][r]);
        }
  } else {
    f16* cp = contF + ((size_t)b * 2048 + (size_t)(rt - 2) * 128) * H_ + (size_t)ct * 128;
#pragma unroll
    for (int i = 0; i < 4; ++i)
#pragma unroll
      for (int j = 0; j < 4; ++j)
#pragma unroll
        for (int r = 0; r < 4; ++r) {
          int row = wr * 64 + i * 16 + quad * 4 + r;
          int col = wc * 64 + j * 16 + l16;
          cp[(size_t)row * H_ + col] = (f16)sane(acc[i][j][r]);
        }
  }
}

// ---------------------------------------------------------------------------
// GEMM2 (unchanged from round 3): 256x128 tile, BK=64, 8 waves, tri-buffered
// LDS, distance-2 prefetch, counted vmcnt(6). Fused relu(+b1)*W2 epilogue.
// ---------------------------------------------------------------------------
__global__ __launch_bounds__(512) void gemm2(const f16* __restrict__ contF,
                                             const f16* __restrict__ W1T,
                                             const float* __restrict__ b1,
                                             const float* __restrict__ W2,
                                             float* __restrict__ scores) {
  __shared__ f16 As[3][256 * 64];   // 3 x 32KB
  __shared__ f16 Bs[3][128 * 64];   // 3 x 16KB
  const int tid = threadIdx.x;
  const uint_t pid = blockIdx.x;
  const int xcd = pid & 7;
  const int s_  = pid >> 3;
  const int ct  = s_ & 7;           // 0..7  (col tile of 128)
  const int g   = s_ >> 3;          // 0..15
  const int rt  = g * 8 + xcd;      // 0..127 (row tile of 256)

  const f16* Ap = contF + (size_t)rt * 256 * H_;
  const f16* Bp = W1T + (size_t)ct * 128 * H_;

  const int lane = tid & 63, w = tid >> 6;   // 8 waves
  const int wm = w >> 1;                     // 0..3  (64-row band)
  const int wn = w & 1;                      // 0..1  (64-col band)
  const int quad = lane >> 4, l16 = lane & 15;
  const int lrow = lane >> 3;                // staging: 8 rows per call
  const int lchk = lane & 7;                 // staging: phys chunk

  f32x4 acc[4][4];
#pragma unroll
  for (int i = 0; i < 4; ++i)
#pragma unroll
    for (int j = 0; j < 4; ++j) acc[i][j] = (f32x4){0.f, 0.f, 0.f, 0.f};

  // ---- prologue: stage K-tiles 0 and 1 ----
#pragma unroll
  for (int t = 0; t < 2; ++t) {
    const int k0 = t * 64;
#pragma unroll
    for (int j = 0; j < 4; ++j) {            // A: 4 calls x 8 rows per wave
      const int rowb = w * 32 + j * 8;
      const int row  = rowb + lrow;
      const int c    = lchk ^ (row & 7);
      load_lds16(Ap + (size_t)row * H_ + k0 + c * 8, &As[t][rowb * 64]);
    }
#pragma unroll
    for (int j = 0; j < 2; ++j) {            // B: 2 calls x 8 rows per wave
      const int rowb = w * 16 + j * 8;
      const int row  = rowb + lrow;
      const int c    = lchk ^ (row & 7);
      load_lds16(Bp + (size_t)row * H_ + k0 + c * 8, &Bs[t][rowb * 64]);
    }
  }
  asm volatile("s_waitcnt vmcnt(0)" ::: "memory");
  __syncthreads();

  // ---- main loop: 16 K-tiles, distance-2 prefetch, counted vmcnt ----
  for (int kt = 0; kt < 16; ++kt) {
    const int rb = kt % 3;
    if (kt + 2 < 16) {
      const int sb = (kt + 2) % 3;
      const int k0 = (kt + 2) * 64;
#pragma unroll
      for (int j = 0; j < 4; ++j) {
        const int rowb = w * 32 + j * 8;
        const int row  = rowb + lrow;
        const int c    = lchk ^ (row & 7);
        load_lds16(Ap + (size_t)row * H_ + k0 + c * 8, &As[sb][rowb * 64]);
      }
#pragma unroll
      for (int j = 0; j < 2; ++j) {
        const int rowb = w * 16 + j * 8;
        const int row  = rowb + lrow;
        const int c    = lchk ^ (row & 7);
        load_lds16(Bp + (size_t)row * H_ + k0 + c * 8, &Bs[sb][rowb * 64]);
      }
    }
    // fragment reads (swizzled) + MFMA on current tile
    f16x8 af[2][4], bf[2][4];
#pragma unroll
    for (int ks = 0; ks < 2; ++ks) {
#pragma unroll
      for (int mf = 0; mf < 4; ++mf) {
        const int row = wm * 64 + mf * 16 + l16;
        const int c   = ks * 4 + quad;
        af[ks][mf] = *(const f16x8*)&As[rb][row * 64 + ((c ^ (row & 7)) * 8)];
      }
#pragma unroll
      for (int nf = 0; nf < 4; ++nf) {
        const int row = wn * 64 + nf * 16 + l16;
        const int c   = ks * 4 + quad;
        bf[ks][nf] = *(const f16x8*)&Bs[rb][row * 64 + ((c ^ (row & 7)) * 8)];
      }
    }
#pragma unroll
    for (int ks = 0; ks < 2; ++ks)
#pragma unroll
      for (int mf = 0; mf < 4; ++mf)
#pragma unroll
        for (int nf = 0; nf < 4; ++nf)
          acc[mf][nf] = __builtin_amdgcn_mfma_f32_16x16x32_f16(
              af[ks][mf], bf[ks][nf], acc[mf][nf], 0, 0, 0);
    // steady state: leave exactly the just-issued kt+2 group (6) in flight
    if (kt <= 13) asm volatile("s_waitcnt vmcnt(6) lgkmcnt(0)" ::: "memory");
    else          asm volatile("s_waitcnt vmcnt(0) lgkmcnt(0)" ::: "memory");
    __builtin_amdgcn_s_barrier();
    __builtin_amdgcn_sched_barrier(0);
  }

  // ---- fused epilogue: relu(+b1)*W2, 16-lane reduce, atomicAdd ----
  const int colbase = ct * 128 + wn * 64;
#pragma unroll
  for (int mf = 0; mf < 4; ++mf) {
#pragma unroll
    for (int r = 0; r < 4; ++r) {
      float t = 0.f;
#pragma unroll
      for (int nf = 0; nf < 4; ++nf) {
        int c = colbase + nf * 16 + l16;
        float v = acc[mf][nf][r] + b1[c];
        v = fmaxf(v, 0.f);
        t = fmaf(v, W2[c], t);
      }
      t += __shfl_xor(t, 1);
      t += __shfl_xor(t, 2);
      t += __shfl_xor(t, 4);
      t += __shfl_xor(t, 8);
      if (l16 == 0) {
        int row = rt * 256 + wm * 64 + mf * 16 + quad * 4 + r;
        atomicAdd(&scores[row], t);
      }
    }
  }
}

// ---------------------------------------------------------------------------
// finalize: mask + softmax over m, weighted sum over cont, ling + width emb
// grid 2048 (one span), 256 thr
// ---------------------------------------------------------------------------
__global__ __launch_bounds__(256) void finalize(const f16* __restrict__ contF,
                                                const float* __restrict__ scores,
                                                const float* __restrict__ ling,
                                                const float* __restrict__ b2,
                                                const float* __restrict__ wtab,
                                                const int* __restrict__ width,
                                                float* __restrict__ out) {
  const int n = blockIdx.x;
  const int tid = threadIdx.x;
  __shared__ float sc[16];
  if (tid < 16) {
    float raw = scores[n * 16 + tid] + b2[0];
    if (raw != raw) raw = 0.0f;            // NaN guard (diagnostic safety)
    int wv = width[n];
    int wm = wv > 1 ? wv : 1;
    float s = (tid < wm) ? raw : 0.0f;     // scores * masks
    if (s == 0.0f) s = -9e9f;              // where(scores != 0, scores, -9e9)
    sc[tid] = s;
  }
  __syncthreads();
  float mx = sc[0];
#pragma unroll
  for (int m = 1; m < 16; ++m) mx = fmaxf(mx, sc[m]);
  float e[16];
  float ssum = 0.f;
#pragma unroll
  for (int m = 0; m < 16; ++m) { e[m] = __expf(sc[m] - mx); ssum += e[m]; }
  const float inv = 1.0f / ssum;
  const f16* cp = contF + (size_t)n * (M_ * H_);
  float* op = out + (size_t)n * OUTW;
#pragma unroll
  for (int hh = 0; hh < 4; ++hh) {
    int h = tid + hh * 256;
    float a = 0.f;
#pragma unroll
    for (int m = 0; m < 16; ++m) a = fmaf(e[m], (float)cp[m * H_ + h], a);
    op[2048 + h] = sane(a * inv);
  }
  if (tid < 2) op[3072 + tid] = ling[n * 2 + tid];
  if (tid < 20) {
    int wv = width[n];
    int wcl = wv < 4 ? wv : 4;
    if (wcl < 0) wcl = 0;
    op[3074 + tid] = wtab[wcl * 20 + tid];
  }
}

// ---------------------------------------------------------------------------
extern "C" void kernel_launch(void* const* d_in, const int* in_sizes, int n_in,
                              void* d_out, int out_size, void* d_ws, size_t ws_size,
                              hipStream_t stream) {
  const float* doc    = (const float*)d_in[0];
  const float* startm = (const float*)d_in[1];
  const float* endm   = (const float*)d_in[2];
  const float* contm  = (const float*)d_in[3];
  const float* ling   = (const float*)d_in[4];
  const float* W1     = (const float*)d_in[5];
  const float* b1     = (const float*)d_in[6];
  const float* W2     = (const float*)d_in[7];
  const float* b2     = (const float*)d_in[8];
  const float* wtab   = (const float*)d_in[9];
  const int*   width  = (const int*)d_in[10];
  float* out = (float*)d_out;

  char* ws = (char*)d_ws;
  f16*      contF  = (f16*)(ws + WS_CONT);
  ushort_t* docT   = (ushort_t*)(ws + WS_DOCT);
  f16*      W1T    = (f16*)(ws + WS_W1T);
  float*    scores = (float*)(ws + WS_SCORES);

  hipMemsetAsync(scores, 0, NROW * sizeof(float), stream);
  tconv<<<dim3(16, 16, 16), 256, 0, stream>>>(doc, docT, 1024, 1024);
  tconv<<<dim3(16, 16, 1), 256, 0, stream>>>(W1, (ushort_t*)W1T, 1024, 1024);
  gemm1<<<dim3(2304, 1, 1), 256, 0, stream>>>(startm, endm, contm, docT, out, contF);
  gemm2<<<dim3(1024, 1, 1), 512, 0, stream>>>(contF, (const f16*)W1T, b1, W2, scores);
  finalize<<<dim3(NSPAN, 1, 1), 256, 0, stream>>>(contF, scores, ling, b2, wtab, width, out);
}

// Round 5
// 488.125 us; speedup vs baseline: 1.1433x; 1.1433x over previous
//
#include <hip/hip_runtime.h>

typedef unsigned short ushort_t;
typedef unsigned int uint_t;
typedef _Float16 f16;
typedef f16 f16x8 __attribute__((ext_vector_type(8)));
typedef float f32x4 __attribute__((ext_vector_type(4)));

#define B_   16
#define S_   128
#define T_   1024
#define M_   16
#define H_   1024
#define OUTW 3094
#define NSPAN (B_*S_)      /* 2048  */
#define NROW  (NSPAN*M_)   /* 32768 */

// ---------- ws layout (bytes) ----------
#define WS_CONT   0                       /* f16  [32768][1024]   67,108,864 B */
#define WS_DOCT   67108864                /* f16  [16][1024][1024] 33,554,432 B */
#define WS_W1T    100663296               /* f16  [1024][1024]     2,097,152 B */
#define WS_SCORES 102760448               /* f32  [32768]            131,072 B */

// clamp that also kills NaN (fmaxf/fminf return the non-NaN operand)
__device__ __forceinline__ float sane(float v) {
  return fminf(fmaxf(v, -60000.f), 60000.f);
}
__device__ __forceinline__ ushort_t f16bits(float f) {
  union { f16 h; ushort_t u; } c; c.h = (f16)f; return c.u;
}
__device__ __forceinline__ void load_lds16(const void* g, void* l) {
  __builtin_amdgcn_global_load_lds(
      (const __attribute__((address_space(1))) uint_t*)g,
      (__attribute__((address_space(3))) uint_t*)l, 16, 0, 0);
}

// ---------------------------------------------------------------------------
// Transpose + f32->f16 convert: in f32 [z][R][C] -> out f16 [z][C][R]
// ---------------------------------------------------------------------------
__global__ __launch_bounds__(256) void tconv(const float* __restrict__ in,
                                             ushort_t* __restrict__ out,
                                             int R, int C) {
  __shared__ uint_t tile[64][65];
  const int tid = threadIdx.x;
  const int c0 = blockIdx.x * 64, r0 = blockIdx.y * 64;
  const size_t mo = (size_t)blockIdx.z * R * C;
  const float* ip = in + mo;
  ushort_t* op = out + mo;
  const int tx = tid & 63, ty = tid >> 6;
#pragma unroll
  for (int p = 0; p < 16; ++p) {
    int r = p * 4 + ty;
    tile[r][tx] = (uint_t)f16bits(ip[(size_t)(r0 + r) * C + c0 + tx]);
  }
  __syncthreads();
  const int rr = (tid & 31) * 2, cc0 = tid >> 5;  // cc0 in 0..7
  uint_t* op32 = (uint_t*)op;
#pragma unroll
  for (int p = 0; p < 8; ++p) {
    int c = cc0 + p * 8;
    uint_t lo = tile[rr][c] & 0xffffu;
    uint_t hi = tile[rr + 1][c] & 0xffffu;
    op32[((size_t)(c0 + c) * R + r0 + rr) >> 1] = lo | (hi << 16);
  }
}

// ---------------------------------------------------------------------------
// GEMM1 (reverted to the proven R0 version, best measured 191 us):
// rows [start(128)|end(128)|cont(2048)] per batch (f32, cvt in-kernel)
//        x docT_b (f16).  start/end -> d_out (f32), cont -> ws (f16)
// 1-D grid 2304 = (8 ct, 18 rt, 16 b), XCD-swizzled; chunk-XOR LDS.
// ---------------------------------------------------------------------------
__global__ __launch_bounds__(256) void gemm1(const float* __restrict__ startm,
                                             const float* __restrict__ endm,
                                             const float* __restrict__ contm,
                                             const ushort_t* __restrict__ docT,
                                             float* __restrict__ out,
                                             f16* __restrict__ contF) {
  __shared__ float As[128 * 32];      // f32 A tile, 16 KB, 8x16B chunks/row
  __shared__ ushort_t Bs[128 * 32];   // f16 B tile,  8 KB, 4x16B chunks/row
  const int tid = threadIdx.x;
  const uint_t pid = blockIdx.x;
  const int xcd = pid & 7;
  const int s_  = pid >> 3;
  const int ct  = s_ & 7;
  const int pg  = (s_ >> 3) * 8 + xcd;   // 0..287
  const int rt  = pg >> 4;
  const int b   = pg & 15;

  const float* Ap;
  if (rt == 0)      Ap = startm + (size_t)b * S_ * T_;
  else if (rt == 1) Ap = endm + (size_t)b * S_ * T_;
  else              Ap = contm + (size_t)b * (S_ * M_ * T_) + (size_t)(rt - 2) * 128 * T_;
  const ushort_t* Bp = docT + (size_t)b * (H_ * T_) + (size_t)ct * 128 * T_;

  const int lane = tid & 63, w = tid >> 6;
  const int wr = w >> 1, wc = w & 1;
  const int quad = lane >> 4, l16 = lane & 15;
  // staging source coords (chunk-swizzled)
  const int arow = lane >> 3;                       // A: 8 rows/call
  const int acol = ((lane & 7) ^ arow) * 4;         // phys chunk = c ^ (row&7)
  const int brow = lane >> 2;                       // B: 16 rows/call
  const int bcol = ((lane & 3) ^ ((lane >> 3) & 3)) * 8;  // c ^ ((row>>1)&3)

  f32x4 acc[4][4];
#pragma unroll
  for (int i = 0; i < 4; ++i)
#pragma unroll
    for (int j = 0; j < 4; ++j) acc[i][j] = (f32x4){0.f, 0.f, 0.f, 0.f};

  for (int k0 = 0; k0 < T_; k0 += 32) {
#pragma unroll
    for (int i = 0; i < 4; ++i) {     // A: 4 calls x 8 rows
      const int rb = w * 32 + i * 8;
      load_lds16(Ap + (size_t)(rb + arow) * T_ + k0 + acol, &As[rb * 32]);
    }
#pragma unroll
    for (int i = 0; i < 2; ++i) {     // B: 2 calls x 16 rows
      const int rb = w * 32 + i * 16;
      load_lds16(Bp + (size_t)(rb + brow) * T_ + k0 + bcol, &Bs[rb * 32]);
    }
    __syncthreads();
    f16x8 af[4], bfr[4];
#pragma unroll
    for (int i = 0; i < 4; ++i) {
      const int row = wr * 64 + i * 16 + l16;
      const int sw = row & 7;
      f32x4 lo = *(const f32x4*)&As[row * 32 + (((quad * 2) ^ sw) * 4)];
      f32x4 hi = *(const f32x4*)&As[row * 32 + (((quad * 2 + 1) ^ sw) * 4)];
      f16x8 h;
#pragma unroll
      for (int k = 0; k < 4; ++k) { h[k] = (f16)lo[k]; h[k + 4] = (f16)hi[k]; }
      af[i] = h;
    }
#pragma unroll
    for (int j = 0; j < 4; ++j) {
      const int row = wc * 64 + j * 16 + l16;
      const int sw = (row >> 1) & 3;
      bfr[j] = *(const f16x8*)&Bs[row * 32 + ((quad ^ sw) * 8)];
    }
#pragma unroll
    for (int i = 0; i < 4; ++i)
#pragma unroll
      for (int j = 0; j < 4; ++j)
        acc[i][j] = __builtin_amdgcn_mfma_f32_16x16x32_f16(af[i], bfr[j], acc[i][j], 0, 0, 0);
    __syncthreads();
  }

  if (rt < 2) {
    float* op = out + (size_t)b * S_ * OUTW + (size_t)rt * 1024 + (size_t)ct * 128;
#pragma unroll
    for (int i = 0; i < 4; ++i)
#pragma unroll
      for (int j = 0; j < 4; ++j)
#pragma unroll
        for (int r = 0; r < 4; ++r) {
          int row = wr * 64 + i * 16 + quad * 4 + r;
          int col = wc * 64 + j * 16 + l16;
          op[(size_t)row * OUTW + col] = sane(acc[i][j][r]);
        }
  } else {
    f16* cp = contF + ((size_t)b * 2048 + (size_t)(rt - 2) * 128) * H_ + (size_t)ct * 128;
#pragma unroll
    for (int i = 0; i < 4; ++i)
#pragma unroll
      for (int j = 0; j < 4; ++j)
#pragma unroll
        for (int r = 0; r < 4; ++r) {
          int row = wr * 64 + i * 16 + quad * 4 + r;
          int col = wc * 64 + j * 16 + l16;
          cp[(size_t)row * H_ + col] = (f16)sane(acc[i][j][r]);
        }
  }
}

// ---------------------------------------------------------------------------
// GEMM2 (ROUND 5): 128x256 tile, 8 waves (512 thr), BK=32, proven 2-barrier
// sync. ct tiles 8 -> 4: contF logical reads halve (536->268 MB), B staging
// per FLOP halves, atomic contention halves. Same chunk-swizzle family as R0
// (16-row-aligned calls, c ^ ((row>>1)&3)). LDS 24KB -> 4 blocks/CU at
// grid 1024 = (8 xcd) x (4 ct) x (32 g), rt = g*8+xcd (0..255).
// Fused relu(+b1)*W2 row-reduce -> atomicAdd into scores[32768].
// ---------------------------------------------------------------------------
__global__ __launch_bounds__(512) void gemm2(const f16* __restrict__ contF,
                                             const f16* __restrict__ W1T,
                                             const float* __restrict__ b1,
                                             const float* __restrict__ W2,
                                             float* __restrict__ scores) {
  __shared__ f16 As[128 * 32];   // 8 KB
  __shared__ f16 Bs[256 * 32];   // 16 KB
  const int tid = threadIdx.x;
  const uint_t pid = blockIdx.x;
  const int xcd = pid & 7;
  const int s_  = pid >> 3;        // 0..127
  const int ct  = s_ & 3;          // 0..3   (col tile of 256)
  const int g   = s_ >> 2;         // 0..31
  const int rt  = g * 8 + xcd;     // 0..255 (row tile of 128)

  const f16* Ap = contF + (size_t)rt * 128 * H_;
  const f16* Bp = W1T + (size_t)ct * 256 * H_;

  const int lane = tid & 63, w = tid >> 6;   // 8 waves
  const int wr = w >> 2;                     // 0..1 (64-row band)
  const int wc = w & 3;                      // 0..3 (64-col band)
  const int quad = lane >> 4, l16 = lane & 15;
  // staging coords: each wave-call covers 16 rows (16-row aligned base),
  // lane -> row base + (lane>>2), logical chunk = (lane&3) ^ ((row>>1)&3)
  const int srow = lane >> 2;                               // 0..15
  const int scol = ((lane & 3) ^ ((lane >> 3) & 3)) * 8;    // f16 offset

  f32x4 acc[4][4];
#pragma unroll
  for (int i = 0; i < 4; ++i)
#pragma unroll
    for (int j = 0; j < 4; ++j) acc[i][j] = (f32x4){0.f, 0.f, 0.f, 0.f};

  for (int k0 = 0; k0 < H_; k0 += 32) {
    // A: 1 call x 16 rows per wave (8 waves x 16 = 128 rows)
    {
      const int rb = w * 16;
      load_lds16(Ap + (size_t)(rb + srow) * H_ + k0 + scol, &As[rb * 32]);
    }
    // B: 2 calls x 16 rows per wave (8 waves x 2 x 16 = 256 rows)
#pragma unroll
    for (int i = 0; i < 2; ++i) {
      const int rb = i * 128 + w * 16;
      load_lds16(Bp + (size_t)(rb + srow) * H_ + k0 + scol, &Bs[rb * 32]);
    }
    __syncthreads();
    f16x8 af[4], bfr[4];
#pragma unroll
    for (int i = 0; i < 4; ++i) {
      const int row = wr * 64 + i * 16 + l16;
      const int sw = (row >> 1) & 3;
      af[i] = *(const f16x8*)&As[row * 32 + ((quad ^ sw) * 8)];
    }
#pragma unroll
    for (int j = 0; j < 4; ++j) {
      const int row = wc * 64 + j * 16 + l16;
      const int sw = (row >> 1) & 3;
      bfr[j] = *(const f16x8*)&Bs[row * 32 + ((quad ^ sw) * 8)];
    }
#pragma unroll
    for (int i = 0; i < 4; ++i)
#pragma unroll
      for (int j = 0; j < 4; ++j)
        acc[i][j] = __builtin_amdgcn_mfma_f32_16x16x32_f16(af[i], bfr[j], acc[i][j], 0, 0, 0);
    __syncthreads();
  }

  const int colbase = ct * 256 + wc * 64;
#pragma unroll
  for (int i = 0; i < 4; ++i) {
#pragma unroll
    for (int r = 0; r < 4; ++r) {
      float t = 0.f;
#pragma unroll
      for (int j = 0; j < 4; ++j) {
        int c = colbase + j * 16 + l16;
        float v = acc[i][j][r] + b1[c];
        v = fmaxf(v, 0.f);
        t = fmaf(v, W2[c], t);
      }
      t += __shfl_xor(t, 1);
      t += __shfl_xor(t, 2);
      t += __shfl_xor(t, 4);
      t += __shfl_xor(t, 8);
      if (l16 == 0) {
        int row = rt * 128 + wr * 64 + i * 16 + quad * 4 + r;
        atomicAdd(&scores[row], t);
      }
    }
  }
}

// ---------------------------------------------------------------------------
// finalize: mask + softmax over m, weighted sum over cont, ling + width emb
// grid 2048 (one span), 256 thr
// ---------------------------------------------------------------------------
__global__ __launch_bounds__(256) void finalize(const f16* __restrict__ contF,
                                                const float* __restrict__ scores,
                                                const float* __restrict__ ling,
                                                const float* __restrict__ b2,
                                                const float* __restrict__ wtab,
                                                const int* __restrict__ width,
                                                float* __restrict__ out) {
  const int n = blockIdx.x;
  const int tid = threadIdx.x;
  __shared__ float sc[16];
  if (tid < 16) {
    float raw = scores[n * 16 + tid] + b2[0];
    if (raw != raw) raw = 0.0f;            // NaN guard (diagnostic safety)
    int wv = width[n];
    int wm = wv > 1 ? wv : 1;
    float s = (tid < wm) ? raw : 0.0f;     // scores * masks
    if (s == 0.0f) s = -9e9f;              // where(scores != 0, scores, -9e9)
    sc[tid] = s;
  }
  __syncthreads();
  float mx = sc[0];
#pragma unroll
  for (int m = 1; m < 16; ++m) mx = fmaxf(mx, sc[m]);
  float e[16];
  float ssum = 0.f;
#pragma unroll
  for (int m = 0; m < 16; ++m) { e[m] = __expf(sc[m] - mx); ssum += e[m]; }
  const float inv = 1.0f / ssum;
  const f16* cp = contF + (size_t)n * (M_ * H_);
  float* op = out + (size_t)n * OUTW;
#pragma unroll
  for (int hh = 0; hh < 4; ++hh) {
    int h = tid + hh * 256;
    float a = 0.f;
#pragma unroll
    for (int m = 0; m < 16; ++m) a = fmaf(e[m], (float)cp[m * H_ + h], a);
    op[2048 + h] = sane(a * inv);
  }
  if (tid < 2) op[3072 + tid] = ling[n * 2 + tid];
  if (tid < 20) {
    int wv = width[n];
    int wcl = wv < 4 ? wv : 4;
    if (wcl < 0) wcl = 0;
    op[3074 + tid] = wtab[wcl * 20 + tid];
  }
}

// ---------------------------------------------------------------------------
extern "C" void kernel_launch(void* const* d_in, const int* in_sizes, int n_in,
                              void* d_out, int out_size, void* d_ws, size_t ws_size,
                              hipStream_t stream) {
  const float* doc    = (const float*)d_in[0];
  const float* startm = (const float*)d_in[1];
  const float* endm   = (const float*)d_in[2];
  const float* contm  = (const float*)d_in[3];
  const float* ling   = (const float*)d_in[4];
  const float* W1     = (const float*)d_in[5];
  const float* b1     = (const float*)d_in[6];
  const float* W2     = (const float*)d_in[7];
  const float* b2     = (const float*)d_in[8];
  const float* wtab   = (const float*)d_in[9];
  const int*   width  = (const int*)d_in[10];
  float* out = (float*)d_out;

  char* ws = (char*)d_ws;
  f16*      contF  = (f16*)(ws + WS_CONT);
  ushort_t* docT   = (ushort_t*)(ws + WS_DOCT);
  f16*      W1T    = (f16*)(ws + WS_W1T);
  float*    scores = (float*)(ws + WS_SCORES);

  hipMemsetAsync(scores, 0, NROW * sizeof(float), stream);
  tconv<<<dim3(16, 16, 16), 256, 0, stream>>>(doc, docT, 1024, 1024);
  tconv<<<dim3(16, 16, 1), 256, 0, stream>>>(W1, (ushort_t*)W1T, 1024, 1024);
  gemm1<<<dim3(2304, 1, 1), 256, 0, stream>>>(startm, endm, contm, docT, out, contF);
  gemm2<<<dim3(1024, 1, 1), 512, 0, stream>>>(contF, (const f16*)W1T, b1, W2, scores);
  finalize<<<dim3(NSPAN, 1, 1), 256, 0, stream>>>(contF, scores, ling, b2, wtab, width, out);
}